// Round 9
// baseline (1427.967 us; speedup 1.0000x reference)
//
#include <hip/hip_runtime.h>
#include <hip/hip_bf16.h>
#include <cstdint>

// ---------------- bf16 helpers ----------------
__device__ __forceinline__ float b2f(unsigned short u) {
    unsigned int t = ((unsigned int)u) << 16;
    float f;
    __builtin_memcpy(&f, &t, 4);
    return f;
}
__device__ __forceinline__ unsigned short f2b(float f) {
    unsigned int u;
    __builtin_memcpy(&u, &f, 4);
    unsigned int r = (u + 0x7FFFu + ((u >> 16) & 1u)) >> 16;
    return (unsigned short)r;
}
// packed f32x2 -> bf16x2 via compiler-lowered v_cvt_pk_bf16_f32 (RNE)
__device__ __forceinline__ unsigned int pkbf(float a, float b) {
    __hip_bfloat162 t = __float22bfloat162_rn(float2{a, b});
    unsigned int u;
    __builtin_memcpy(&u, &t, 4);
    return u;
}
__device__ __forceinline__ float2 bpair(unsigned int u) {
    float2 r;
    unsigned int lo = u << 16;
    unsigned int hi = u & 0xFFFF0000u;
    __builtin_memcpy(&r.x, &lo, 4);
    __builtin_memcpy(&r.y, &hi, 4);
    return r;
}

typedef __attribute__((ext_vector_type(8))) short bf16x8;
typedef __attribute__((ext_vector_type(4))) float f32x4;

#define LOG2E 1.4426950408889634f
#define SC2   0.2550348595f   /* (1/sqrt(32)) * log2(e) */

// ---------------- weight transpose + fp32->bf16 convert (once per call) ----------------
__global__ void transcvt_k(const float* __restrict__ in,
                           unsigned short* __restrict__ out, int R, int C,
                           int in_z, int out_z) {
    __shared__ float tile[32][33];
    in += (size_t)blockIdx.z * in_z;
    out += (size_t)blockIdx.z * out_z;
    const int c0 = blockIdx.x * 32, r0 = blockIdx.y * 32;
    const int tx = threadIdx.x, ty = threadIdx.y;
#pragma unroll
    for (int i = 0; i < 32; i += 8)
        tile[ty + i][tx] = in[(size_t)(r0 + ty + i) * C + c0 + tx];
    __syncthreads();
#pragma unroll
    for (int i = 0; i < 32; i += 8)
        out[(size_t)(c0 + ty + i) * R + r0 + tx] = f2b(tile[tx][ty + i]);
}

// ---------------- sph -> bf16 * log2e, key-permuted within 64-tiles ----------------
// Key k -> slot 4*(k&15) + ((k>>4)&3): a lane's 4 bias values for one q-row
// {lq, lq+16, lq+32, lq+48} are one contiguous uint2.
__global__ __launch_bounds__(256) void sph_cvt_perm(const float* __restrict__ in,
                                                    unsigned short* __restrict__ out) {
    const int t = threadIdx.x & 127;
    const size_t row = (size_t)blockIdx.x * 2 + (threadIdx.x >> 7);
    const int g = t >> 2, q = t & 3;
    const float* ip = in + row * 2048 + 64 * g + 4 * q;
    float4 f0 = *(const float4*)(ip);
    float4 f1 = *(const float4*)(ip + 16);
    float4 f2 = *(const float4*)(ip + 32);
    float4 f3 = *(const float4*)(ip + 48);
    uint4 o0, o1;
    o0.x = pkbf(f0.x * LOG2E, f1.x * LOG2E); o0.y = pkbf(f2.x * LOG2E, f3.x * LOG2E);
    o0.z = pkbf(f0.y * LOG2E, f1.y * LOG2E); o0.w = pkbf(f2.y * LOG2E, f3.y * LOG2E);
    o1.x = pkbf(f0.z * LOG2E, f1.z * LOG2E); o1.y = pkbf(f2.z * LOG2E, f3.z * LOG2E);
    o1.z = pkbf(f0.w * LOG2E, f1.w * LOG2E); o1.w = pkbf(f2.w * LOG2E, f3.w * LOG2E);
    unsigned short* op = out + row * 2048 + 64 * g + 16 * q;
    ((uint4*)op)[0] = o0;
    ((uint4*)op)[1] = o1;
}

// ---------------- fp32 -> bf16 convert (initial XB) ----------------
__global__ __launch_bounds__(256) void cvt_bf16_k(const float* __restrict__ in,
                                                  unsigned short* __restrict__ out) {
    const size_t idx = (size_t)blockIdx.x * 256 + threadIdx.x;
    const float4 a = ((const float4*)in)[idx * 2];
    const float4 b = ((const float4*)in)[idx * 2 + 1];
    uint4 o;
    o.x = pkbf(a.x, a.y);
    o.y = pkbf(a.z, a.w);
    o.z = pkbf(b.x, b.y);
    o.w = pkbf(b.z, b.w);
    ((uint4*)out)[idx] = o;
}

// ---------------- GEMM: reg-staged double-buffered, BK=32, 1 barrier/iter ----------------
// C[M,N] = A[M,K] @ Wt[N,K]^T + bias (+gelu). Tile 128 x TN, 4 waves 2x2.
// RESID: epilogue additionally adds the bf16 residual read from C itself
// (C[row,col] holds x pre-call; per-element read-before-write in-thread, rows
// disjoint across blocks -> race-free). Produces the raw pre-LN sum in C.
template <int TN, int QKVB, int RESID>
__global__ __launch_bounds__(256) void gemm_db_kernel(
    const unsigned short* __restrict__ A, const unsigned short* __restrict__ Wt,
    const float* __restrict__ biasQ, const float* __restrict__ biasK,
    const float* __restrict__ biasV, unsigned short* __restrict__ C,
    int M, int N, int K, int do_gelu) {
    constexpr int JN = TN / 32;          // 16-col B frags per wave
    __shared__ unsigned short As[2][128 * 32];
    __shared__ unsigned short Bs[2][TN * 32];
    const int tid = threadIdx.x;
    const int lane = tid & 63, wid = tid >> 6;
    const int m0 = blockIdx.y * 128, n0 = blockIdx.x * TN;
    const int wm = (wid >> 1) * 64, wn = (wid & 1) * (TN / 2);
    const int quad = lane >> 4, mrow = lane & 15;
    f32x4 acc[4][JN] = {};

    // staging maps: A = 128 rows x 32 cols, 2 threads/row x 2 slots (8 shorts each)
    const int arow = tid >> 1, asl = (tid & 1) * 2;
    const unsigned short* Ag = A + (size_t)(m0 + arow) * K + asl * 8;
    int brow, bsl;
    if constexpr (TN == 128) { brow = tid >> 1; bsl = (tid & 1) * 2; }
    else                     { brow = tid >> 2; bsl = tid & 3; }
    const unsigned short* Bg = Wt + (size_t)(n0 + brow) * K + bsl * 8;

    // prologue: prefetch tile 0
    uint4 a0 = *(const uint4*)(Ag);
    uint4 a1 = *(const uint4*)(Ag + 8);
    uint4 b0 = *(const uint4*)(Bg);
    uint4 b1 = {};
    if constexpr (TN == 128) b1 = *(const uint4*)(Bg + 8);
    int c = 0;

    for (int kb = 0; kb < K; kb += 32) {
        // store prefetched tile -> LDS[c] (swizzled: slot s at ((s^(row&3))<<3))
        *(uint4*)&As[c][arow * 32 + ((asl ^ (arow & 3)) << 3)] = a0;
        *(uint4*)&As[c][arow * 32 + (((asl + 1) ^ (arow & 3)) << 3)] = a1;
        if constexpr (TN == 128) {
            *(uint4*)&Bs[c][brow * 32 + ((bsl ^ (brow & 3)) << 3)] = b0;
            *(uint4*)&Bs[c][brow * 32 + (((bsl + 1) ^ (brow & 3)) << 3)] = b1;
        } else {
            *(uint4*)&Bs[c][brow * 32 + ((bsl ^ (brow & 3)) << 3)] = b0;
        }
        // issue next tile's global loads; latency hides under compute below
        if (kb + 32 < K) {
            a0 = *(const uint4*)(Ag + kb + 32);
            a1 = *(const uint4*)(Ag + kb + 40);
            b0 = *(const uint4*)(Bg + kb + 32);
            if constexpr (TN == 128) b1 = *(const uint4*)(Bg + kb + 40);
        }
        __syncthreads();

        bf16x8 af[4], bfr[JN];
#pragma unroll
        for (int i = 0; i < 4; i++) {
            const int ar = wm + i * 16 + mrow;
            af[i] = *(const bf16x8*)&As[c][ar * 32 + ((quad ^ (ar & 3)) << 3)];
        }
#pragma unroll
        for (int j = 0; j < JN; j++) {
            const int br = wn + j * 16 + mrow;
            bfr[j] = *(const bf16x8*)&Bs[c][br * 32 + ((quad ^ (br & 3)) << 3)];
        }
        __builtin_amdgcn_s_setprio(1);
#pragma unroll
        for (int i = 0; i < 4; i++)
#pragma unroll
            for (int j = 0; j < JN; j++)
                acc[i][j] = __builtin_amdgcn_mfma_f32_16x16x32_bf16(af[i], bfr[j], acc[i][j], 0, 0, 0);
        __builtin_amdgcn_s_setprio(0);
        c ^= 1;
    }

    const float* bp;
    if (QKVB) {
        const int bsel = n0 >> 8;
        bp = bsel == 0 ? biasQ : (bsel == 1 ? biasK : biasV);
    } else {
        bp = biasQ;
    }
#pragma unroll
    for (int i = 0; i < 4; i++)
#pragma unroll
        for (int j = 0; j < JN; j++) {
            const int col = n0 + wn + j * 16 + mrow;
            const float bv = QKVB ? bp[col & 255] : bp[col];
            const int row = m0 + wm + i * 16 + quad * 4;
            float v[4];
#pragma unroll
            for (int r = 0; r < 4; r++) {
                v[r] = acc[i][j][r] + bv;
                if (RESID) v[r] += b2f(C[(size_t)(row + r) * N + col]);
                if (do_gelu) v[r] = 0.5f * v[r] * (1.0f + erff(v[r] * 0.70710678118654752f));
            }
#pragma unroll
            for (int r2 = 0; r2 < 4; r2 += 2) {
                const unsigned u = pkbf(v[r2], v[r2 + 1]);
                C[(size_t)(row + r2) * N + col] = (unsigned short)u;
                C[(size_t)(row + r2 + 1) * N + col] = (unsigned short)(u >> 16);
            }
        }
}

// ---------------- attention: flash MFMA, T14 double-buffered staging ----------------
// (round-7 version — verified 135 us; FROZEN)
template <int SPHB16>
__global__ __launch_bounds__(256) void attn_mfma(
    const unsigned short* __restrict__ Qb, const unsigned short* __restrict__ Kb,
    const unsigned short* __restrict__ Vb, const float* __restrict__ sphf,
    const unsigned short* __restrict__ sphb, unsigned short* __restrict__ Ctx) {
    __shared__ unsigned short Ks[2 * 64 * 40];
    __shared__ unsigned short Vt[2 * 32 * 72];
    __shared__ unsigned short Ps[4][16 * 72];

    const int tid = threadIdx.x, lane = tid & 63, wid = tid >> 6;
    const int quad = lane >> 4, lq = lane & 15;
    const int bid = blockIdx.x;
    const int h = bid >> 8, b = (bid >> 5) & 7, qt = bid & 31;
    const int q0 = qt * 64;
    const size_t bS = (size_t)b * 2048;

    const int skey = tid >> 2, sdg = (tid & 3) << 3;
    const unsigned short* kp = Kb + (bS + skey) * 768 + h * 32 + sdg;
    const int vkp = tid & 31, vdg = (tid >> 5) << 2;
    const int vm = vkp & 15, vc = vkp >> 4;
    const int vso = 2 * vm + 32 * vc;
    const unsigned short* vp = Vb + (bS + vm + 32 * vc) * 768 + h * 32 + vdg;

    const bf16x8 qf = *(const bf16x8*)(Qb + (bS + q0 + wid * 16 + lq) * 768 + h * 32 + quad * 8);

    const size_t sprow = ((size_t)b * 2048 + q0 + wid * 16 + quad * 4) * 2048;
    const float* spf = sphf + sprow + lq;
    const unsigned short* spb = sphb + sprow + 4 * lq;

    float l_r[4] = {0.f, 0.f, 0.f, 0.f};
    f32x4 o0 = {}, o1 = {};

    uint4 kw = *(const uint4*)kp;
    uint2 va = *(const uint2*)vp;
    uint2 vb2 = *(const uint2*)(vp + 16 * 768);
    int c = 0;

    for (int kt = 0; kt < 32; ++kt) {
        *(uint4*)&Ks[c * 2560 + skey * 40 + sdg] = kw;
        {
            unsigned short* vt = &Vt[c * 2304];
            *(unsigned int*)&vt[(vdg + 0) * 72 + vso] = (va.x & 0xFFFFu) | (vb2.x << 16);
            *(unsigned int*)&vt[(vdg + 1) * 72 + vso] = (va.x >> 16) | (vb2.x & 0xFFFF0000u);
            *(unsigned int*)&vt[(vdg + 2) * 72 + vso] = (va.y & 0xFFFFu) | (vb2.y << 16);
            *(unsigned int*)&vt[(vdg + 3) * 72 + vso] = (va.y >> 16) | (vb2.y & 0xFFFF0000u);
        }
        if (kt < 31) {
            kp += 64 * 768;
            vp += 64 * 768;
            kw = *(const uint4*)kp;
            va = *(const uint2*)vp;
            vb2 = *(const uint2*)(vp + 16 * 768);
        }
        __syncthreads();

        const unsigned short* ks = &Ks[c * 2560];
        const unsigned short* vt = &Vt[c * 2304];
        const f32x4 zf = {};
        __builtin_amdgcn_s_setprio(1);
        f32x4 sa0 = __builtin_amdgcn_mfma_f32_16x16x32_bf16(
            qf, *(const bf16x8*)&ks[(0  + lq) * 40 + quad * 8], zf, 0, 0, 0);
        f32x4 sa1 = __builtin_amdgcn_mfma_f32_16x16x32_bf16(
            qf, *(const bf16x8*)&ks[(16 + lq) * 40 + quad * 8], zf, 0, 0, 0);
        f32x4 sa2 = __builtin_amdgcn_mfma_f32_16x16x32_bf16(
            qf, *(const bf16x8*)&ks[(32 + lq) * 40 + quad * 8], zf, 0, 0, 0);
        f32x4 sa3 = __builtin_amdgcn_mfma_f32_16x16x32_bf16(
            qf, *(const bf16x8*)&ks[(48 + lq) * 40 + quad * 8], zf, 0, 0, 0);
        __builtin_amdgcn_s_setprio(0);

        const int k0 = kt * 64;
#pragma unroll
        for (int r = 0; r < 4; ++r) {
            float sb0, sb1, sb2, sb3;
            if (SPHB16) {
                const uint2 su = *(const uint2*)(spb + (size_t)r * 2048 + k0);
                const float2 slo = bpair(su.x), shi = bpair(su.y);
                sb0 = slo.x; sb1 = slo.y; sb2 = shi.x; sb3 = shi.y;
            } else {
                const float* spr = spf + (size_t)r * 2048 + k0;
                sb0 = spr[0]  * LOG2E; sb1 = spr[16] * LOG2E;
                sb2 = spr[32] * LOG2E; sb3 = spr[48] * LOG2E;
            }
            const float p0 = __builtin_amdgcn_exp2f(fmaf(sa0[r], SC2, sb0));
            const float p1 = __builtin_amdgcn_exp2f(fmaf(sa1[r], SC2, sb1));
            const float p2 = __builtin_amdgcn_exp2f(fmaf(sa2[r], SC2, sb2));
            const float p3 = __builtin_amdgcn_exp2f(fmaf(sa3[r], SC2, sb3));
            l_r[r] += (p0 + p1) + (p2 + p3);
            unsigned int* pw = (unsigned int*)&Ps[wid][(quad * 4 + r) * 72];
            pw[lq]      = pkbf(p0, p1);
            pw[lq + 16] = pkbf(p2, p3);
        }

        __builtin_amdgcn_s_setprio(1);
#pragma unroll
        for (int k2 = 0; k2 < 2; ++k2) {
            bf16x8 pf = *(const bf16x8*)&Ps[wid][lq * 72 + k2 * 32 + quad * 8];
            o0 = __builtin_amdgcn_mfma_f32_16x16x32_bf16(
                pf, *(const bf16x8*)&vt[(0  + lq) * 72 + k2 * 32 + quad * 8], o0, 0, 0, 0);
            o1 = __builtin_amdgcn_mfma_f32_16x16x32_bf16(
                pf, *(const bf16x8*)&vt[(16 + lq) * 72 + k2 * 32 + quad * 8], o1, 0, 0, 0);
        }
        __builtin_amdgcn_s_setprio(0);
        c ^= 1;
    }

    unsigned short* op = Ctx + (bS + q0 + wid * 16 + quad * 4) * 256 + h * 32;
#pragma unroll
    for (int r = 0; r < 4; ++r) {
        float l = l_r[r];
        l += __shfl_xor(l, 1);
        l += __shfl_xor(l, 2);
        l += __shfl_xor(l, 4);
        l += __shfl_xor(l, 8);
        const float inv = 1.f / l;
        op[r * 256 + lq]      = f2b(o0[r] * inv);
        op[r * 256 + 16 + lq] = f2b(o1[r] * inv);
    }
}

// ---------------- pure LayerNorm over the raw bf16 sum (in-place) ----------------
// t2 holds v = x + s (bf16). Non-final: t2 <- bf16(LN(v)) in place (same-element
// read-then-write per thread; rows disjoint across waves/blocks). Final: write
// fp32 LN(v) to fout instead (no bf16 update needed).
template <int FINAL>
__global__ __launch_bounds__(256) void ln_only_kernel(
    unsigned short* t2, const float* __restrict__ g, const float* __restrict__ be,
    float* __restrict__ fout) {
    const int lane = threadIdx.x & 63, wid = threadIdx.x >> 6;
    const size_t row = (size_t)blockIdx.x * 4 + wid;
    uint2 ru = *(const uint2*)(t2 + row * 256 + lane * 4);
    float2 ra = bpair(ru.x), rb = bpair(ru.y);
    float v[4] = {ra.x, ra.y, rb.x, rb.y};
    float sum = v[0] + v[1] + v[2] + v[3];
#pragma unroll
    for (int off = 32; off; off >>= 1) sum += __shfl_xor(sum, off);
    const float mu = sum * (1.f / 256.f);
    float sq = 0.f;
#pragma unroll
    for (int i = 0; i < 4; i++) { float d = v[i] - mu; sq += d * d; }
#pragma unroll
    for (int off = 32; off; off >>= 1) sq += __shfl_xor(sq, off);
    const float rs = rsqrtf(sq * (1.f / 256.f) + 1e-5f);
    float4 o;
    o.x = (v[0] - mu) * rs * g[lane * 4 + 0] + be[lane * 4 + 0];
    o.y = (v[1] - mu) * rs * g[lane * 4 + 1] + be[lane * 4 + 1];
    o.z = (v[2] - mu) * rs * g[lane * 4 + 2] + be[lane * 4 + 2];
    o.w = (v[3] - mu) * rs * g[lane * 4 + 3] + be[lane * 4 + 3];
    if (FINAL) {
        *(float4*)(fout + row * 256 + lane * 4) = o;
    } else {
        uint2 p;
        p.x = pkbf(o.x, o.y);
        p.y = pkbf(o.z, o.w);
        *(uint2*)(t2 + row * 256 + lane * 4) = p;
    }
}

// ---------------- launch ----------------
extern "C" void kernel_launch(void* const* d_in, const int* in_sizes, int n_in,
                              void* d_out, int out_size, void* d_ws, size_t ws_size,
                              hipStream_t stream) {
    const float* src = (const float*)d_in[0];
    const float* sph = (const float*)d_in[1];
    const float* Wq  = (const float*)d_in[2];
    const float* bq  = (const float*)d_in[3];
    const float* Wk  = (const float*)d_in[4];
    const float* bk  = (const float*)d_in[5];
    const float* Wv  = (const float*)d_in[6];
    const float* bv  = (const float*)d_in[7];
    const float* Wo  = (const float*)d_in[8];
    const float* bo  = (const float*)d_in[9];
    const float* W1  = (const float*)d_in[10];
    const float* b1  = (const float*)d_in[11];
    const float* W2  = (const float*)d_in[12];
    const float* b2  = (const float*)d_in[13];
    const float* g1  = (const float*)d_in[14];
    const float* be1 = (const float*)d_in[15];
    const float* g2  = (const float*)d_in[16];
    const float* be2 = (const float*)d_in[17];

    char* ws = (char*)d_ws;
    unsigned short* QKV = (unsigned short*)(ws + 0);        // 16384 x 768 bf16 (25.2MB)
    unsigned short* CTX = (unsigned short*)(ws + 25165824); // 16384 x 256
    unsigned short* T2  = (unsigned short*)(ws + 33554432); // 16384 x 256 — residual stream (=XB)
    unsigned short* H   = QKV;                              // 16384x1024 bf16 reuses QKV+CTX
    unsigned short* XB  = T2;                               // bf16 residual (post-LN x, or raw sum)
    unsigned short* WtQKV = (unsigned short*)(ws + 41943040); // 5 x 768 x 256
    unsigned short* WtO   = (unsigned short*)(ws + 43909120); // 5 x 256 x 256
    unsigned short* Wt1   = (unsigned short*)(ws + 44564480); // 5 x 1024 x 256
    unsigned short* Wt2   = (unsigned short*)(ws + 47185920); // 5 x 256 x 1024
    unsigned short* SPHB  = (unsigned short*)(ws + 50331648); // 8x2048x2048 bf16 (67MB), permuted
    const int use_b16 = (ws_size >= (size_t)117440512);

    const dim3 tb(32, 8);
    transcvt_k<<<dim3(8, 8, 5),  tb, 0, stream>>>(Wq, WtQKV,          256, 256, 65536, 196608);
    transcvt_k<<<dim3(8, 8, 5),  tb, 0, stream>>>(Wk, WtQKV + 65536,  256, 256, 65536, 196608);
    transcvt_k<<<dim3(8, 8, 5),  tb, 0, stream>>>(Wv, WtQKV + 131072, 256, 256, 65536, 196608);
    transcvt_k<<<dim3(8, 8, 5),  tb, 0, stream>>>(Wo, WtO,            256, 256, 65536, 65536);
    transcvt_k<<<dim3(32, 8, 5), tb, 0, stream>>>(W1, Wt1,            256, 1024, 262144, 262144);
    transcvt_k<<<dim3(8, 32, 5), tb, 0, stream>>>(W2, Wt2,            1024, 256, 262144, 262144);
    if (use_b16) sph_cvt_perm<<<8192, 256, 0, stream>>>(sph, SPHB);
    cvt_bf16_k<<<2048, 256, 0, stream>>>(src, XB);   // initial residual = bf16(src)

    const int M = 16384;
    for (int lyr = 0; lyr < 5; ++lyr) {
        // 1. QKV projection (reads XB = post-LN x, or bf16 src at layer 0)
        gemm_db_kernel<128, 1, 0><<<dim3(6, 128), 256, 0, stream>>>(
            XB, WtQKV + lyr * 196608, bq + lyr * 256, bk + lyr * 256, bv + lyr * 256,
            QKV, M, 768, 256, 0);
        // 2. attention
        if (use_b16)
            attn_mfma<1><<<2048, 256, 0, stream>>>(QKV, QKV + 256, QKV + 512, sph, SPHB, CTX);
        else
            attn_mfma<0><<<2048, 256, 0, stream>>>(QKV, QKV + 256, QKV + 512, sph, SPHB, CTX);
        // 3. output projection + residual: T2 = CTX@Wo + bo + XB   (XB==T2, in-place add)
        gemm_db_kernel<64, 0, 1><<<dim3(4, 128), 256, 0, stream>>>(
            CTX, WtO + lyr * 65536, bo + lyr * 256, nullptr, nullptr, T2, M, 256, 256, 0);
        // 4. XB = bf16(LN1(T2)) in place
        ln_only_kernel<0><<<4096, 256, 0, stream>>>(T2, g1 + lyr * 256, be1 + lyr * 256, nullptr);
        // 5. FFN1 (reads XB) -> H, gelu
        gemm_db_kernel<128, 0, 0><<<dim3(8, 128), 256, 0, stream>>>(
            XB, Wt1 + lyr * 262144, b1 + lyr * 1024, nullptr, nullptr, H, M, 1024, 256, 1);
        // 6. FFN2 + residual: T2 = H@W2 + b2 + XB   (in-place add)
        gemm_db_kernel<64, 0, 1><<<dim3(4, 128), 256, 0, stream>>>(
            H, Wt2 + lyr * 262144, b2 + lyr * 256, nullptr, nullptr, T2, M, 256, 1024, 0);
        // 7. LN2: last layer writes fp32 d_out; otherwise XB = bf16(LN2(T2))
        if (lyr == 4)
            ln_only_kernel<1><<<4096, 256, 0, stream>>>(T2, g2 + lyr * 256, be2 + lyr * 256,
                                                        (float*)d_out);
        else
            ln_only_kernel<0><<<4096, 256, 0, stream>>>(T2, g2 + lyr * 256, be2 + lyr * 256,
                                                        nullptr);
    }
}

// Round 10
// 1348.366 us; speedup vs baseline: 1.0590x; 1.0590x over previous
//
#include <hip/hip_runtime.h>
#include <hip/hip_bf16.h>
#include <cstdint>

// ---------------- bf16 helpers ----------------
__device__ __forceinline__ float b2f(unsigned short u) {
    unsigned int t = ((unsigned int)u) << 16;
    float f;
    __builtin_memcpy(&f, &t, 4);
    return f;
}
__device__ __forceinline__ unsigned short f2b(float f) {
    unsigned int u;
    __builtin_memcpy(&u, &f, 4);
    unsigned int r = (u + 0x7FFFu + ((u >> 16) & 1u)) >> 16;
    return (unsigned short)r;
}
// packed f32x2 -> bf16x2 via compiler-lowered v_cvt_pk_bf16_f32 (RNE)
__device__ __forceinline__ unsigned int pkbf(float a, float b) {
    __hip_bfloat162 t = __float22bfloat162_rn(float2{a, b});
    unsigned int u;
    __builtin_memcpy(&u, &t, 4);
    return u;
}
__device__ __forceinline__ float2 bpair(unsigned int u) {
    float2 r;
    unsigned int lo = u << 16;
    unsigned int hi = u & 0xFFFF0000u;
    __builtin_memcpy(&r.x, &lo, 4);
    __builtin_memcpy(&r.y, &hi, 4);
    return r;
}

typedef __attribute__((ext_vector_type(8))) short bf16x8;
typedef __attribute__((ext_vector_type(4))) float f32x4;

#define LOG2E 1.4426950408889634f
#define SC2   0.2550348595f   /* (1/sqrt(32)) * log2(e) */

// ---------------- weight transpose + fp32->bf16 convert (once per call) ----------------
__global__ void transcvt_k(const float* __restrict__ in,
                           unsigned short* __restrict__ out, int R, int C,
                           int in_z, int out_z) {
    __shared__ float tile[32][33];
    in += (size_t)blockIdx.z * in_z;
    out += (size_t)blockIdx.z * out_z;
    const int c0 = blockIdx.x * 32, r0 = blockIdx.y * 32;
    const int tx = threadIdx.x, ty = threadIdx.y;
#pragma unroll
    for (int i = 0; i < 32; i += 8)
        tile[ty + i][tx] = in[(size_t)(r0 + ty + i) * C + c0 + tx];
    __syncthreads();
#pragma unroll
    for (int i = 0; i < 32; i += 8)
        out[(size_t)(c0 + ty + i) * R + r0 + tx] = f2b(tile[tx][ty + i]);
}

// ---------------- sph -> bf16 * log2e, key-permuted within 64-tiles ----------------
// Key k -> slot 4*(k&15) + ((k>>4)&3): a lane's 4 bias values for one q-row
// {lq, lq+16, lq+32, lq+48} are one contiguous uint2.
__global__ __launch_bounds__(256) void sph_cvt_perm(const float* __restrict__ in,
                                                    unsigned short* __restrict__ out) {
    const int t = threadIdx.x & 127;
    const size_t row = (size_t)blockIdx.x * 2 + (threadIdx.x >> 7);
    const int g = t >> 2, q = t & 3;
    const float* ip = in + row * 2048 + 64 * g + 4 * q;
    float4 f0 = *(const float4*)(ip);
    float4 f1 = *(const float4*)(ip + 16);
    float4 f2 = *(const float4*)(ip + 32);
    float4 f3 = *(const float4*)(ip + 48);
    uint4 o0, o1;
    o0.x = pkbf(f0.x * LOG2E, f1.x * LOG2E); o0.y = pkbf(f2.x * LOG2E, f3.x * LOG2E);
    o0.z = pkbf(f0.y * LOG2E, f1.y * LOG2E); o0.w = pkbf(f2.y * LOG2E, f3.y * LOG2E);
    o1.x = pkbf(f0.z * LOG2E, f1.z * LOG2E); o1.y = pkbf(f2.z * LOG2E, f3.z * LOG2E);
    o1.z = pkbf(f0.w * LOG2E, f1.w * LOG2E); o1.w = pkbf(f2.w * LOG2E, f3.w * LOG2E);
    unsigned short* op = out + row * 2048 + 64 * g + 16 * q;
    ((uint4*)op)[0] = o0;
    ((uint4*)op)[1] = o1;
}

// ---------------- fp32 -> bf16 convert + fp32 copy (initial X / XB) ----------------
__global__ __launch_bounds__(256) void cvt_bf16_k(const float* __restrict__ in,
                                                  unsigned short* __restrict__ out,
                                                  float* __restrict__ xcopy) {
    const size_t idx = (size_t)blockIdx.x * 256 + threadIdx.x;
    const float4 a = ((const float4*)in)[idx * 2];
    const float4 b = ((const float4*)in)[idx * 2 + 1];
    uint4 o;
    o.x = pkbf(a.x, a.y);
    o.y = pkbf(a.z, a.w);
    o.z = pkbf(b.x, b.y);
    o.w = pkbf(b.z, b.w);
    ((uint4*)out)[idx] = o;
    ((float4*)xcopy)[idx * 2] = a;
    ((float4*)xcopy)[idx * 2 + 1] = b;
}

// ---------------- GEMM: reg-staged double-buffered, BK=32, 1 barrier/iter ----------------
// C[M,N] = A[M,K] @ Wt[N,K]^T + bias (+gelu). Tile 128 x TN, 4 waves 2x2.
template <int TN, int QKVB>
__global__ __launch_bounds__(256) void gemm_db_kernel(
    const unsigned short* __restrict__ A, const unsigned short* __restrict__ Wt,
    const float* __restrict__ biasQ, const float* __restrict__ biasK,
    const float* __restrict__ biasV, unsigned short* __restrict__ C,
    int M, int N, int K, int do_gelu) {
    constexpr int JN = TN / 32;          // 16-col B frags per wave
    __shared__ unsigned short As[2][128 * 32];
    __shared__ unsigned short Bs[2][TN * 32];
    const int tid = threadIdx.x;
    const int lane = tid & 63, wid = tid >> 6;
    const int m0 = blockIdx.y * 128, n0 = blockIdx.x * TN;
    const int wm = (wid >> 1) * 64, wn = (wid & 1) * (TN / 2);
    const int quad = lane >> 4, mrow = lane & 15;
    f32x4 acc[4][JN] = {};

    // staging maps: A = 128 rows x 32 cols, 2 threads/row x 2 slots (8 shorts each)
    const int arow = tid >> 1, asl = (tid & 1) * 2;
    const unsigned short* Ag = A + (size_t)(m0 + arow) * K + asl * 8;
    int brow, bsl;
    if constexpr (TN == 128) { brow = tid >> 1; bsl = (tid & 1) * 2; }
    else                     { brow = tid >> 2; bsl = tid & 3; }
    const unsigned short* Bg = Wt + (size_t)(n0 + brow) * K + bsl * 8;

    // prologue: prefetch tile 0
    uint4 a0 = *(const uint4*)(Ag);
    uint4 a1 = *(const uint4*)(Ag + 8);
    uint4 b0 = *(const uint4*)(Bg);
    uint4 b1 = {};
    if constexpr (TN == 128) b1 = *(const uint4*)(Bg + 8);
    int c = 0;

    for (int kb = 0; kb < K; kb += 32) {
        // store prefetched tile -> LDS[c] (swizzled: slot s at ((s^(row&3))<<3))
        *(uint4*)&As[c][arow * 32 + ((asl ^ (arow & 3)) << 3)] = a0;
        *(uint4*)&As[c][arow * 32 + (((asl + 1) ^ (arow & 3)) << 3)] = a1;
        if constexpr (TN == 128) {
            *(uint4*)&Bs[c][brow * 32 + ((bsl ^ (brow & 3)) << 3)] = b0;
            *(uint4*)&Bs[c][brow * 32 + (((bsl + 1) ^ (brow & 3)) << 3)] = b1;
        } else {
            *(uint4*)&Bs[c][brow * 32 + ((bsl ^ (brow & 3)) << 3)] = b0;
        }
        // issue next tile's global loads; latency hides under compute below
        if (kb + 32 < K) {
            a0 = *(const uint4*)(Ag + kb + 32);
            a1 = *(const uint4*)(Ag + kb + 40);
            b0 = *(const uint4*)(Bg + kb + 32);
            if constexpr (TN == 128) b1 = *(const uint4*)(Bg + kb + 40);
        }
        __syncthreads();

        bf16x8 af[4], bfr[JN];
#pragma unroll
        for (int i = 0; i < 4; i++) {
            const int ar = wm + i * 16 + mrow;
            af[i] = *(const bf16x8*)&As[c][ar * 32 + ((quad ^ (ar & 3)) << 3)];
        }
#pragma unroll
        for (int j = 0; j < JN; j++) {
            const int br = wn + j * 16 + mrow;
            bfr[j] = *(const bf16x8*)&Bs[c][br * 32 + ((quad ^ (br & 3)) << 3)];
        }
        __builtin_amdgcn_s_setprio(1);
#pragma unroll
        for (int i = 0; i < 4; i++)
#pragma unroll
            for (int j = 0; j < JN; j++)
                acc[i][j] = __builtin_amdgcn_mfma_f32_16x16x32_bf16(af[i], bfr[j], acc[i][j], 0, 0, 0);
        __builtin_amdgcn_s_setprio(0);
        c ^= 1;
    }

    const float* bp;
    if (QKVB) {
        const int bsel = n0 >> 8;
        bp = bsel == 0 ? biasQ : (bsel == 1 ? biasK : biasV);
    } else {
        bp = biasQ;
    }
#pragma unroll
    for (int i = 0; i < 4; i++)
#pragma unroll
        for (int j = 0; j < JN; j++) {
            const int col = n0 + wn + j * 16 + mrow;
            const float bv = QKVB ? bp[col & 255] : bp[col];
            float v[4];
#pragma unroll
            for (int r = 0; r < 4; r++) {
                v[r] = acc[i][j][r] + bv;
                if (do_gelu) v[r] = 0.5f * v[r] * (1.0f + erff(v[r] * 0.70710678118654752f));
            }
            const int row = m0 + wm + i * 16 + quad * 4;
#pragma unroll
            for (int r2 = 0; r2 < 4; r2 += 2) {
                const unsigned u = pkbf(v[r2], v[r2 + 1]);
                C[(size_t)(row + r2) * N + col] = (unsigned short)u;
                C[(size_t)(row + r2 + 1) * N + col] = (unsigned short)(u >> 16);
            }
        }
}

// ---------------- attention: flash MFMA, T14 double-buffered staging ----------------
// Round-7 structure (frozen) + sph-sharing XCD swizzle: the 8 heads of one
// (b,qt) read the SAME 256KB sph slice. Launch index i -> h=(i>>3)&7,
// rest=((i>>6)<<3)|(i&7): the 8 sharers sit at i, i+8, ..., i+56 — equal mod 8
// (same XCD under round-robin) and within 56 dispatch slots (co-resident) ->
// sph served from L2 for 7 of 8 readers. (Round-6's swizzle did the OPPOSITE:
// consecutive sharers -> 8 different XCDs -> FETCH went up. Bijective: i =
// 64*(rest>>3) + 8*h + (rest&7).)
template <int SPHB16>
__global__ __launch_bounds__(256) void attn_mfma(
    const unsigned short* __restrict__ Qb, const unsigned short* __restrict__ Kb,
    const unsigned short* __restrict__ Vb, const float* __restrict__ sphf,
    const unsigned short* __restrict__ sphb, unsigned short* __restrict__ Ctx) {
    __shared__ unsigned short Ks[2 * 64 * 40];
    __shared__ unsigned short Vt[2 * 32 * 72];
    __shared__ unsigned short Ps[4][16 * 72];

    const int tid = threadIdx.x, lane = tid & 63, wid = tid >> 6;
    const int quad = lane >> 4, lq = lane & 15;
    const int bid0 = blockIdx.x;
    const int h = (bid0 >> 3) & 7;
    const int rest = ((bid0 >> 6) << 3) | (bid0 & 7);
    const int b = rest >> 5, qt = rest & 31;
    const int q0 = qt * 64;
    const size_t bS = (size_t)b * 2048;

    const int skey = tid >> 2, sdg = (tid & 3) << 3;
    const unsigned short* kp = Kb + (bS + skey) * 768 + h * 32 + sdg;
    const int vkp = tid & 31, vdg = (tid >> 5) << 2;
    const int vm = vkp & 15, vc = vkp >> 4;
    const int vso = 2 * vm + 32 * vc;
    const unsigned short* vp = Vb + (bS + vm + 32 * vc) * 768 + h * 32 + vdg;

    const bf16x8 qf = *(const bf16x8*)(Qb + (bS + q0 + wid * 16 + lq) * 768 + h * 32 + quad * 8);

    const size_t sprow = ((size_t)b * 2048 + q0 + wid * 16 + quad * 4) * 2048;
    const float* spf = sphf + sprow + lq;
    const unsigned short* spb = sphb + sprow + 4 * lq;

    float l_r[4] = {0.f, 0.f, 0.f, 0.f};
    f32x4 o0 = {}, o1 = {};

    uint4 kw = *(const uint4*)kp;
    uint2 va = *(const uint2*)vp;
    uint2 vb2 = *(const uint2*)(vp + 16 * 768);
    int c = 0;

    for (int kt = 0; kt < 32; ++kt) {
        *(uint4*)&Ks[c * 2560 + skey * 40 + sdg] = kw;
        {
            unsigned short* vt = &Vt[c * 2304];
            *(unsigned int*)&vt[(vdg + 0) * 72 + vso] = (va.x & 0xFFFFu) | (vb2.x << 16);
            *(unsigned int*)&vt[(vdg + 1) * 72 + vso] = (va.x >> 16) | (vb2.x & 0xFFFF0000u);
            *(unsigned int*)&vt[(vdg + 2) * 72 + vso] = (va.y & 0xFFFFu) | (vb2.y << 16);
            *(unsigned int*)&vt[(vdg + 3) * 72 + vso] = (va.y >> 16) | (vb2.y & 0xFFFF0000u);
        }
        if (kt < 31) {
            kp += 64 * 768;
            vp += 64 * 768;
            kw = *(const uint4*)kp;
            va = *(const uint2*)vp;
            vb2 = *(const uint2*)(vp + 16 * 768);
        }
        __syncthreads();

        const unsigned short* ks = &Ks[c * 2560];
        const unsigned short* vt = &Vt[c * 2304];
        const f32x4 zf = {};
        __builtin_amdgcn_s_setprio(1);
        f32x4 sa0 = __builtin_amdgcn_mfma_f32_16x16x32_bf16(
            qf, *(const bf16x8*)&ks[(0  + lq) * 40 + quad * 8], zf, 0, 0, 0);
        f32x4 sa1 = __builtin_amdgcn_mfma_f32_16x16x32_bf16(
            qf, *(const bf16x8*)&ks[(16 + lq) * 40 + quad * 8], zf, 0, 0, 0);
        f32x4 sa2 = __builtin_amdgcn_mfma_f32_16x16x32_bf16(
            qf, *(const bf16x8*)&ks[(32 + lq) * 40 + quad * 8], zf, 0, 0, 0);
        f32x4 sa3 = __builtin_amdgcn_mfma_f32_16x16x32_bf16(
            qf, *(const bf16x8*)&ks[(48 + lq) * 40 + quad * 8], zf, 0, 0, 0);
        __builtin_amdgcn_s_setprio(0);

        const int k0 = kt * 64;
#pragma unroll
        for (int r = 0; r < 4; ++r) {
            float sb0, sb1, sb2, sb3;
            if (SPHB16) {
                const uint2 su = *(const uint2*)(spb + (size_t)r * 2048 + k0);
                const float2 slo = bpair(su.x), shi = bpair(su.y);
                sb0 = slo.x; sb1 = slo.y; sb2 = shi.x; sb3 = shi.y;
            } else {
                const float* spr = spf + (size_t)r * 2048 + k0;
                sb0 = spr[0]  * LOG2E; sb1 = spr[16] * LOG2E;
                sb2 = spr[32] * LOG2E; sb3 = spr[48] * LOG2E;
            }
            const float p0 = __builtin_amdgcn_exp2f(fmaf(sa0[r], SC2, sb0));
            const float p1 = __builtin_amdgcn_exp2f(fmaf(sa1[r], SC2, sb1));
            const float p2 = __builtin_amdgcn_exp2f(fmaf(sa2[r], SC2, sb2));
            const float p3 = __builtin_amdgcn_exp2f(fmaf(sa3[r], SC2, sb3));
            l_r[r] += (p0 + p1) + (p2 + p3);
            unsigned int* pw = (unsigned int*)&Ps[wid][(quad * 4 + r) * 72];
            pw[lq]      = pkbf(p0, p1);
            pw[lq + 16] = pkbf(p2, p3);
        }

        __builtin_amdgcn_s_setprio(1);
#pragma unroll
        for (int k2 = 0; k2 < 2; ++k2) {
            bf16x8 pf = *(const bf16x8*)&Ps[wid][lq * 72 + k2 * 32 + quad * 8];
            o0 = __builtin_amdgcn_mfma_f32_16x16x32_bf16(
                pf, *(const bf16x8*)&vt[(0  + lq) * 72 + k2 * 32 + quad * 8], o0, 0, 0, 0);
            o1 = __builtin_amdgcn_mfma_f32_16x16x32_bf16(
                pf, *(const bf16x8*)&vt[(16 + lq) * 72 + k2 * 32 + quad * 8], o1, 0, 0, 0);
        }
        __builtin_amdgcn_s_setprio(0);
        c ^= 1;
    }

    unsigned short* op = Ctx + (bS + q0 + wid * 16 + quad * 4) * 256 + h * 32;
#pragma unroll
    for (int r = 0; r < 4; ++r) {
        float l = l_r[r];
        l += __shfl_xor(l, 1);
        l += __shfl_xor(l, 2);
        l += __shfl_xor(l, 4);
        l += __shfl_xor(l, 8);
        const float inv = 1.f / l;
        op[r * 256 + lq]      = f2b(o0[r] * inv);
        op[r * 256 + 16 + lq] = f2b(o1[r] * inv);
    }
}

// ---------------- fused residual + LayerNorm (fp32 stream + bf16 copy) ----------------
// NOTE: r and xb may ALIAS (XB == T2).
__global__ __launch_bounds__(256) void add_ln_kernel(
    const float* x, const unsigned short* r,
    const float* __restrict__ g, const float* __restrict__ be,
    float* out, unsigned short* xb) {
    const int lane = threadIdx.x & 63, wid = threadIdx.x >> 6;
    const size_t row = (size_t)blockIdx.x * 4 + wid;
    float4 xv = *(const float4*)(x + row * 256 + lane * 4);
    uint2 ru = *(const uint2*)(r + row * 256 + lane * 4);
    float2 ra = bpair(ru.x), rb = bpair(ru.y);
    float v[4] = {xv.x + ra.x, xv.y + ra.y, xv.z + rb.x, xv.w + rb.y};
    float sum = v[0] + v[1] + v[2] + v[3];
#pragma unroll
    for (int off = 32; off; off >>= 1) sum += __shfl_xor(sum, off);
    const float mu = sum * (1.f / 256.f);
    float sq = 0.f;
#pragma unroll
    for (int i = 0; i < 4; i++) { float d = v[i] - mu; sq += d * d; }
#pragma unroll
    for (int off = 32; off; off >>= 1) sq += __shfl_xor(sq, off);
    const float rs = rsqrtf(sq * (1.f / 256.f) + 1e-5f);
    float4 o;
    o.x = (v[0] - mu) * rs * g[lane * 4 + 0] + be[lane * 4 + 0];
    o.y = (v[1] - mu) * rs * g[lane * 4 + 1] + be[lane * 4 + 1];
    o.z = (v[2] - mu) * rs * g[lane * 4 + 2] + be[lane * 4 + 2];
    o.w = (v[3] - mu) * rs * g[lane * 4 + 3] + be[lane * 4 + 3];
    *(float4*)(out + row * 256 + lane * 4) = o;
    uint2 p;
    p.x = pkbf(o.x, o.y);
    p.y = pkbf(o.z, o.w);
    *(uint2*)(xb + row * 256 + lane * 4) = p;
}

// ---------------- launch ----------------
extern "C" void kernel_launch(void* const* d_in, const int* in_sizes, int n_in,
                              void* d_out, int out_size, void* d_ws, size_t ws_size,
                              hipStream_t stream) {
    const float* src = (const float*)d_in[0];
    const float* sph = (const float*)d_in[1];
    const float* Wq  = (const float*)d_in[2];
    const float* bq  = (const float*)d_in[3];
    const float* Wk  = (const float*)d_in[4];
    const float* bk  = (const float*)d_in[5];
    const float* Wv  = (const float*)d_in[6];
    const float* bv  = (const float*)d_in[7];
    const float* Wo  = (const float*)d_in[8];
    const float* bo  = (const float*)d_in[9];
    const float* W1  = (const float*)d_in[10];
    const float* b1  = (const float*)d_in[11];
    const float* W2  = (const float*)d_in[12];
    const float* b2  = (const float*)d_in[13];
    const float* g1  = (const float*)d_in[14];
    const float* be1 = (const float*)d_in[15];
    const float* g2  = (const float*)d_in[16];
    const float* be2 = (const float*)d_in[17];

    char* ws = (char*)d_ws;
    float* X = (float*)d_out;                               // fp32 activations in d_out
    unsigned short* QKV = (unsigned short*)(ws + 0);        // 16384 x 768 bf16 (25.2MB)
    unsigned short* CTX = (unsigned short*)(ws + 25165824); // 16384 x 256
    unsigned short* T2  = (unsigned short*)(ws + 33554432); // 16384 x 256 (ALSO = XB)
    unsigned short* H   = QKV;                              // 16384x1024 bf16 reuses QKV+CTX
    unsigned short* XB  = T2;                               // bf16 residual-stream copy (aliased)
    unsigned short* WtQKV = (unsigned short*)(ws + 41943040); // 5 x 768 x 256
    unsigned short* WtO   = (unsigned short*)(ws + 43909120); // 5 x 256 x 256
    unsigned short* Wt1   = (unsigned short*)(ws + 44564480); // 5 x 1024 x 256
    unsigned short* Wt2   = (unsigned short*)(ws + 47185920); // 5 x 256 x 1024
    unsigned short* SPHB  = (unsigned short*)(ws + 50331648); // 8x2048x2048 bf16 (67MB), permuted
    const int use_b16 = (ws_size >= (size_t)117440512);

    const dim3 tb(32, 8);
    transcvt_k<<<dim3(8, 8, 5),  tb, 0, stream>>>(Wq, WtQKV,          256, 256, 65536, 196608);
    transcvt_k<<<dim3(8, 8, 5),  tb, 0, stream>>>(Wk, WtQKV + 65536,  256, 256, 65536, 196608);
    transcvt_k<<<dim3(8, 8, 5),  tb, 0, stream>>>(Wv, WtQKV + 131072, 256, 256, 65536, 196608);
    transcvt_k<<<dim3(8, 8, 5),  tb, 0, stream>>>(Wo, WtO,            256, 256, 65536, 65536);
    transcvt_k<<<dim3(32, 8, 5), tb, 0, stream>>>(W1, Wt1,            256, 1024, 262144, 262144);
    transcvt_k<<<dim3(8, 32, 5), tb, 0, stream>>>(W2, Wt2,            1024, 256, 262144, 262144);
    if (use_b16) sph_cvt_perm<<<8192, 256, 0, stream>>>(sph, SPHB);
    cvt_bf16_k<<<2048, 256, 0, stream>>>(src, XB, X);  // bf16 copy + fp32 copy fused

    const int M = 16384;
    for (int lyr = 0; lyr < 5; ++lyr) {
        // 1. QKV projection (reads XB=T2; T2 free to clobber afterwards)
        gemm_db_kernel<128, 1><<<dim3(6, 128), 256, 0, stream>>>(
            XB, WtQKV + lyr * 196608, bq + lyr * 256, bk + lyr * 256, bv + lyr * 256,
            QKV, M, 768, 256, 0);
        // 2. attention
        if (use_b16)
            attn_mfma<1><<<2048, 256, 0, stream>>>(QKV, QKV + 256, QKV + 512, sph, SPHB, CTX);
        else
            attn_mfma<0><<<2048, 256, 0, stream>>>(QKV, QKV + 256, QKV + 512, sph, SPHB, CTX);
        // 3. output projection -> T2 (clobbers XB; old XB already consumed)
        gemm_db_kernel<64, 0><<<dim3(4, 128), 256, 0, stream>>>(
            CTX, WtO + lyr * 65536, bo + lyr * 256, nullptr, nullptr, T2, M, 256, 256, 0);
        // 4. x = LN(x + T2); writes fp32 X and bf16 XB(=T2, in-place)
        add_ln_kernel<<<4096, 256, 0, stream>>>(X, T2, g1 + lyr * 256, be1 + lyr * 256, X, XB);
        // 5. FFN1 (reads XB) -> H, gelu
        gemm_db_kernel<128, 0><<<dim3(8, 128), 256, 0, stream>>>(
            XB, Wt1 + lyr * 262144, b1 + lyr * 1024, nullptr, nullptr, H, M, 1024, 256, 1);
        // 6. FFN2 -> T2 (clobbers XB; already consumed by FFN1)
        gemm_db_kernel<64, 0><<<dim3(4, 128), 256, 0, stream>>>(
            H, Wt2 + lyr * 262144, b2 + lyr * 256, nullptr, nullptr, T2, M, 256, 1024, 0);
        // 7. x = LN(x + T2); refresh XB
        add_ln_kernel<<<4096, 256, 0, stream>>>(X, T2, g2 + lyr * 256, be2 + lyr * 256, X, XB);
    }
}